// Round 3
// baseline (483.536 us; speedup 1.0000x reference)
//
#include <hip/hip_runtime.h>

#define NFEAT 128
#define NGRAPH 64

// ---------------- degree histogram ----------------
__global__ void k_deg(const int* __restrict__ dst, unsigned int* __restrict__ cnt, int nE) {
    int e = blockIdx.x * blockDim.x + threadIdx.x;
    if (e < nE) atomicAdd(&cnt[dst[e]], 1u);
}

// dinv[i] = 1/sqrt(deg_with_self_loop)
__global__ void k_dinv(const unsigned int* __restrict__ cnt, float* __restrict__ dinv, int nN) {
    int i = blockIdx.x * blockDim.x + threadIdx.x;
    if (i < nN) dinv[i] = 1.0f / sqrtf((float)(cnt[i] + 1u));
}

// ---------------- 3-kernel exclusive scan (50000 elems) ----------------
__global__ void k_scan1(const unsigned int* __restrict__ cnt, unsigned int* __restrict__ bsum, int nN) {
    __shared__ unsigned int ws[4];
    int i = blockIdx.x * 256 + threadIdx.x;
    unsigned int v = (i < nN) ? cnt[i] : 0u;
    for (int d = 32; d; d >>= 1) v += __shfl_down(v, d, 64);
    if ((threadIdx.x & 63) == 0) ws[threadIdx.x >> 6] = v;
    __syncthreads();
    if (threadIdx.x == 0) bsum[blockIdx.x] = ws[0] + ws[1] + ws[2] + ws[3];
}

__global__ void k_scan2(const unsigned int* __restrict__ bsum, unsigned int* __restrict__ boff,
                        int* __restrict__ off, int nb, int nN) {
    __shared__ unsigned int ws[4];
    int t = threadIdx.x;
    unsigned int v = (t < nb) ? bsum[t] : 0u;
    unsigned int s = v;
    for (int d = 1; d < 64; d <<= 1) {
        unsigned int u = __shfl_up(s, d, 64);
        if ((t & 63) >= d) s += u;
    }
    int w = t >> 6;
    if ((t & 63) == 63) ws[w] = s;
    __syncthreads();
    unsigned int woff = 0;
    for (int j = 0; j < w; ++j) woff += ws[j];
    unsigned int excl = woff + s - v;
    if (t < nb) boff[t] = excl;
    if (t == nb - 1) off[nN] = (int)(excl + v);
}

__global__ void k_scan3(const unsigned int* __restrict__ cnt, const unsigned int* __restrict__ boff,
                        int* __restrict__ off, int nN) {
    __shared__ unsigned int ws[4];
    int i = blockIdx.x * 256 + threadIdx.x;
    int t = threadIdx.x;
    unsigned int v = (i < nN) ? cnt[i] : 0u;
    unsigned int s = v;
    for (int d = 1; d < 64; d <<= 1) {
        unsigned int u = __shfl_up(s, d, 64);
        if ((t & 63) >= d) s += u;
    }
    int w = t >> 6;
    if ((t & 63) == 63) ws[w] = s;
    __syncthreads();
    unsigned int woff = 0;
    for (int j = 0; j < w; ++j) woff += ws[j];
    if (i < nN) off[i] = (int)(boff[blockIdx.x] + woff + s - v);
}

// ---------------- CSR scatter (group edges by dst) ----------------
__global__ void k_scatter(const int* __restrict__ src, const int* __restrict__ dst,
                          const int* __restrict__ off, unsigned int* __restrict__ cursor,
                          int* __restrict__ csr, int nE) {
    int e = blockIdx.x * blockDim.x + threadIdx.x;
    if (e >= nE) return;
    int d = dst[e];
    int pos = off[d] + (int)atomicAdd(&cursor[d], 1u);
    csr[pos] = src[e];
}

// ---------------- dense GEMM: Y[n,128] = X[n,128] @ W[128,128] ----------------
__global__ __launch_bounds__(256) void k_gemm(const float* __restrict__ X,
                                              const float* __restrict__ W,
                                              float* __restrict__ Y, int nN) {
    __shared__ float sW[NFEAT * NFEAT];   // 64 KB
    __shared__ float sX[8 * NFEAT];       // 4 KB
    for (int i = threadIdx.x; i < NFEAT * NFEAT; i += 256) sW[i] = W[i];
    int cx = threadIdx.x & 31;   // 32 col-threads x 4 cols each
    int r  = threadIdx.x >> 5;   // 8 rows per block-chunk
    for (int rowBase = blockIdx.x * 8; rowBase < nN; rowBase += gridDim.x * 8) {
        __syncthreads();
        for (int i = threadIdx.x; i < 8 * NFEAT; i += 256) {
            int rr = rowBase + (i >> 7);
            sX[i] = (rr < nN) ? X[(size_t)rowBase * NFEAT + i] : 0.f;
        }
        __syncthreads();
        float a0 = 0.f, a1 = 0.f, a2 = 0.f, a3 = 0.f;
        #pragma unroll 8
        for (int k = 0; k < NFEAT; ++k) {
            float xv = sX[r * NFEAT + k];
            const float4 w = *(const float4*)&sW[k * NFEAT + cx * 4];
            a0 = fmaf(xv, w.x, a0);
            a1 = fmaf(xv, w.y, a1);
            a2 = fmaf(xv, w.z, a2);
            a3 = fmaf(xv, w.w, a3);
        }
        int row = rowBase + r;
        if (row < nN) {
            float4 o4 = make_float4(a0, a1, a2, a3);
            *(float4*)&Y[(size_t)row * NFEAT + cx * 4] = o4;
        }
    }
}

// ---------------- edge aggregation: one wave per node ----------------
// out[i] = relu( sum_{e: dst=i} h[src_e]*dinv[src_e]*dinv[i] + h[i]*dinv[i]^2 + b )
__global__ __launch_bounds__(256) void k_agg(const float* __restrict__ h,
                                             const float* __restrict__ dinv,
                                             const int* __restrict__ off,
                                             const int* __restrict__ csr,
                                             const float* __restrict__ bias,
                                             float* __restrict__ out, int nN) {
    int wave = (blockIdx.x * blockDim.x + threadIdx.x) >> 6;
    int lane = threadIdx.x & 63;
    if (wave >= nN) return;
    const int f2 = lane * 2;  // this lane owns features f2, f2+1
    float di = dinv[wave];
    float a0 = 0.f, a1 = 0.f;
    int j0 = off[wave], j1 = off[wave + 1];
    for (int j = j0; j < j1; ++j) {
        int s = csr[j];
        float w = dinv[s] * di;
        float2 hv = *(const float2*)&h[(size_t)s * NFEAT + f2];
        a0 = fmaf(hv.x, w, a0);
        a1 = fmaf(hv.y, w, a1);
    }
    // self loop
    {
        float ws = di * di;
        float2 hv = *(const float2*)&h[(size_t)wave * NFEAT + f2];
        a0 = fmaf(hv.x, ws, a0);
        a1 = fmaf(hv.y, ws, a1);
    }
    float2 bv = *(const float2*)&bias[f2];
    a0 = fmaxf(a0 + bv.x, 0.f);
    a1 = fmaxf(a1 + bv.y, 0.f);
    float2 o2 = make_float2(a0, a1);
    *(float2*)&out[(size_t)wave * NFEAT + f2] = o2;
}

// ---------------- mean pool over sorted batch ----------------
__global__ void k_pool(const float* __restrict__ h, const int* __restrict__ batch,
                       float* __restrict__ pooled, float* __restrict__ counts, int nN) {
    const int CHUNK = 128;
    int start = blockIdx.x * CHUNK;
    if (start >= nN) return;
    int end = min(start + CHUNK, nN);
    int f = threadIdx.x;  // 128 threads = 128 features
    float sum = 0.f;
    int cnt = 0;
    int cur = batch[start];
    for (int i = start; i < end; ++i) {
        int g = batch[i];
        if (g != cur) {
            atomicAdd(&pooled[cur * NFEAT + f], sum);
            if (f == 0) atomicAdd(&counts[cur], (float)cnt);
            sum = 0.f; cnt = 0; cur = g;
        }
        sum += h[(size_t)i * NFEAT + f];
        cnt++;
    }
    atomicAdd(&pooled[cur * NFEAT + f], sum);
    if (f == 0) atomicAdd(&counts[cur], (float)cnt);
}

// ---------------- classifier head: out[64,2] ----------------
__global__ void k_final(const float* __restrict__ pooled, const float* __restrict__ counts,
                        const float* __restrict__ Wc, const float* __restrict__ bc,
                        float* __restrict__ out) {
    int t = threadIdx.x;  // 128 threads: g = t>>1, class = t&1
    int g = t >> 1, c = t & 1;
    float inv = 1.0f / fmaxf(counts[g], 1.0f);
    float s = 0.f;
    for (int f = 0; f < NFEAT; ++f) s += pooled[g * NFEAT + f] * Wc[f * 2 + c];
    out[t] = s * inv + bc[c];
}

extern "C" void kernel_launch(void* const* d_in, const int* in_sizes, int n_in,
                              void* d_out, int out_size, void* d_ws, size_t ws_size,
                              hipStream_t stream) {
    const float* x   = (const float*)d_in[0];
    const int*   ei  = (const int*)d_in[1];
    const int*   bat = (const int*)d_in[2];
    const float* W1  = (const float*)d_in[3];
    const float* b1  = (const float*)d_in[4];
    const float* W2  = (const float*)d_in[5];
    const float* b2  = (const float*)d_in[6];
    const float* Wc  = (const float*)d_in[7];
    const float* bc  = (const float*)d_in[8];
    float* out = (float*)d_out;

    const int nN = in_sizes[0] / NFEAT;      // 50000
    const int nE = in_sizes[1] / 2;          // 800000
    const int* src = ei;
    const int* dst = ei + nE;

    char* ws = (char*)d_ws;
    size_t o = 0;
    auto alloc = [&](size_t bytes) -> char* {
        char* p = ws + o;
        o = (o + bytes + 255) & ~(size_t)255;
        return p;
    };
    // ---- zeroed region (one memset) ----
    unsigned int* cnt    = (unsigned int*)alloc((size_t)nN * 4);
    unsigned int* cursor = (unsigned int*)alloc((size_t)nN * 4);
    float* pooled        = (float*)alloc((size_t)NGRAPH * NFEAT * 4);
    float* counts        = (float*)alloc((size_t)NGRAPH * 4);
    size_t zero_bytes = o;
    // ---- rest ----
    int* off           = (int*)alloc(((size_t)nN + 1) * 4);
    unsigned int* bsum = (unsigned int*)alloc(256 * 4);
    unsigned int* boff = (unsigned int*)alloc(256 * 4);
    int* csr           = (int*)alloc((size_t)nE * 4);
    float* dinv        = (float*)alloc((size_t)nN * 4);
    float* h1          = (float*)alloc((size_t)nN * NFEAT * 4);
    float* h2          = (float*)alloc((size_t)nN * NFEAT * 4);
    (void)ws_size; (void)n_in; (void)out_size;

    hipMemsetAsync(d_ws, 0, zero_bytes, stream);

    const int nb = (nN + 255) / 256;  // 196 scan blocks

    k_deg<<<(nE + 255) / 256, 256, 0, stream>>>(dst, cnt, nE);
    k_dinv<<<(nN + 255) / 256, 256, 0, stream>>>(cnt, dinv, nN);
    k_scan1<<<nb, 256, 0, stream>>>(cnt, bsum, nN);
    k_scan2<<<1, 256, 0, stream>>>(bsum, boff, off, nb, nN);
    k_scan3<<<nb, 256, 0, stream>>>(cnt, boff, off, nN);
    k_scatter<<<(nE + 255) / 256, 256, 0, stream>>>(src, dst, off, cursor, csr, nE);

    // layer 1: h1 = x @ W1 ; h2 = relu(agg(h1) + b1)
    k_gemm<<<512, 256, 0, stream>>>(x, W1, h1, nN);
    k_agg<<<(nN + 3) / 4, 256, 0, stream>>>(h1, dinv, off, csr, b1, h2, nN);
    // layer 2: h1 = h2 @ W2 ; h2 = relu(agg(h1) + b2)
    k_gemm<<<512, 256, 0, stream>>>(h2, W2, h1, nN);
    k_agg<<<(nN + 3) / 4, 256, 0, stream>>>(h1, dinv, off, csr, b2, h2, nN);

    // mean pool + head
    k_pool<<<(nN + 127) / 128, 128, 0, stream>>>(h2, bat, pooled, counts, nN);
    k_final<<<1, 128, 0, stream>>>(pooled, counts, Wc, bc, out);
}

// Round 5
// 430.346 us; speedup vs baseline: 1.1236x; 1.1236x over previous
//
#include <hip/hip_runtime.h>
#include <hip/hip_fp16.h>

#define NFEAT 128
#define NGRAPH 64

// ---------------- degree histogram ----------------
__global__ void k_deg(const int* __restrict__ dst, unsigned int* __restrict__ cnt, int nE) {
    int e = blockIdx.x * blockDim.x + threadIdx.x;
    if (e < nE) atomicAdd(&cnt[dst[e]], 1u);
}

// dinv[i] = 1/sqrt(deg_with_self_loop)
__global__ void k_dinv(const unsigned int* __restrict__ cnt, float* __restrict__ dinv, int nN) {
    int i = blockIdx.x * blockDim.x + threadIdx.x;
    if (i < nN) dinv[i] = 1.0f / sqrtf((float)(cnt[i] + 1u));
}

// ---------------- 3-kernel exclusive scan (50000 elems) ----------------
__global__ void k_scan1(const unsigned int* __restrict__ cnt, unsigned int* __restrict__ bsum, int nN) {
    __shared__ unsigned int ws[4];
    int i = blockIdx.x * 256 + threadIdx.x;
    unsigned int v = (i < nN) ? cnt[i] : 0u;
    for (int d = 32; d; d >>= 1) v += __shfl_down(v, d, 64);
    if ((threadIdx.x & 63) == 0) ws[threadIdx.x >> 6] = v;
    __syncthreads();
    if (threadIdx.x == 0) bsum[blockIdx.x] = ws[0] + ws[1] + ws[2] + ws[3];
}

__global__ void k_scan2(const unsigned int* __restrict__ bsum, unsigned int* __restrict__ boff,
                        int* __restrict__ off, int nb, int nN) {
    __shared__ unsigned int ws[4];
    int t = threadIdx.x;
    unsigned int v = (t < nb) ? bsum[t] : 0u;
    unsigned int s = v;
    for (int d = 1; d < 64; d <<= 1) {
        unsigned int u = __shfl_up(s, d, 64);
        if ((t & 63) >= d) s += u;
    }
    int w = t >> 6;
    if ((t & 63) == 63) ws[w] = s;
    __syncthreads();
    unsigned int woff = 0;
    for (int j = 0; j < w; ++j) woff += ws[j];
    unsigned int excl = woff + s - v;
    if (t < nb) boff[t] = excl;
    if (t == nb - 1) off[nN] = (int)(excl + v);
}

__global__ void k_scan3(const unsigned int* __restrict__ cnt, const unsigned int* __restrict__ boff,
                        int* __restrict__ off, int nN) {
    __shared__ unsigned int ws[4];
    int i = blockIdx.x * 256 + threadIdx.x;
    int t = threadIdx.x;
    unsigned int v = (i < nN) ? cnt[i] : 0u;
    unsigned int s = v;
    for (int d = 1; d < 64; d <<= 1) {
        unsigned int u = __shfl_up(s, d, 64);
        if ((t & 63) >= d) s += u;
    }
    int w = t >> 6;
    if ((t & 63) == 63) ws[w] = s;
    __syncthreads();
    unsigned int woff = 0;
    for (int j = 0; j < w; ++j) woff += ws[j];
    if (i < nN) off[i] = (int)(boff[blockIdx.x] + woff + s - v);
}

// ---------------- CSR scatter (group edges by dst) ----------------
__global__ void k_scatter(const int* __restrict__ src, const int* __restrict__ dst,
                          const int* __restrict__ off, unsigned int* __restrict__ cursor,
                          int* __restrict__ csr, int nE) {
    int e = blockIdx.x * blockDim.x + threadIdx.x;
    if (e >= nE) return;
    int d = dst[e];
    int pos = off[d] + (int)atomicAdd(&cursor[d], 1u);
    csr[pos] = src[e];
}

// ---------------- dense GEMM: Yh[n,128](fp16) = X[n,128] @ W[128,128] ----------------
// 32 rows/chunk; thread = 4 rows x 4 cols; per k-quad: 8 ds_read_b128 for 64 FMA.
__global__ __launch_bounds__(256) void k_gemm(const float* __restrict__ X,
                                              const float* __restrict__ W,
                                              __half* __restrict__ Yh, int nN) {
    __shared__ float sW[NFEAT * NFEAT];   // 64 KB
    __shared__ float sX[32 * NFEAT];      // 16 KB -> 80 KB total, 2 blocks/CU
    for (int i = threadIdx.x; i < NFEAT * NFEAT; i += 256) sW[i] = W[i];
    const int cx = threadIdx.x & 31;      // cols cx*4 .. +3
    const int rg = threadIdx.x >> 5;      // rows rg*4 .. +3  (8 groups x 4 = 32)
    for (int rowBase = blockIdx.x * 32; rowBase < nN; rowBase += gridDim.x * 32) {
        __syncthreads();
        // stage 32x128 X chunk (coalesced b128, conflict-free b128 LDS writes)
        #pragma unroll
        for (int rr = 0; rr < 4; ++rr) {
            int r = (threadIdx.x >> 5) + rr * 8;
            int row = rowBase + r;
            float4 v = make_float4(0.f, 0.f, 0.f, 0.f);
            if (row < nN) v = *(const float4*)&X[(size_t)row * NFEAT + (threadIdx.x & 31) * 4];
            *(float4*)&sX[r * NFEAT + (threadIdx.x & 31) * 4] = v;
        }
        __syncthreads();
        float4 a0 = make_float4(0.f,0.f,0.f,0.f), a1 = a0, a2 = a0, a3 = a0;
        #pragma unroll 2
        for (int k = 0; k < NFEAT; k += 4) {
            float4 x0 = *(const float4*)&sX[(rg * 4 + 0) * NFEAT + k];
            float4 x1 = *(const float4*)&sX[(rg * 4 + 1) * NFEAT + k];
            float4 x2 = *(const float4*)&sX[(rg * 4 + 2) * NFEAT + k];
            float4 x3 = *(const float4*)&sX[(rg * 4 + 3) * NFEAT + k];
            #pragma unroll
            for (int i = 0; i < 4; ++i) {
                float4 wv = *(const float4*)&sW[(k + i) * NFEAT + cx * 4];
                float s0 = ((const float*)&x0)[i];
                float s1 = ((const float*)&x1)[i];
                float s2 = ((const float*)&x2)[i];
                float s3 = ((const float*)&x3)[i];
                a0.x = fmaf(s0, wv.x, a0.x); a0.y = fmaf(s0, wv.y, a0.y);
                a0.z = fmaf(s0, wv.z, a0.z); a0.w = fmaf(s0, wv.w, a0.w);
                a1.x = fmaf(s1, wv.x, a1.x); a1.y = fmaf(s1, wv.y, a1.y);
                a1.z = fmaf(s1, wv.z, a1.z); a1.w = fmaf(s1, wv.w, a1.w);
                a2.x = fmaf(s2, wv.x, a2.x); a2.y = fmaf(s2, wv.y, a2.y);
                a2.z = fmaf(s2, wv.z, a2.z); a2.w = fmaf(s2, wv.w, a2.w);
                a3.x = fmaf(s3, wv.x, a3.x); a3.y = fmaf(s3, wv.y, a3.y);
                a3.z = fmaf(s3, wv.z, a3.z); a3.w = fmaf(s3, wv.w, a3.w);
            }
        }
        // epilogue: fp16 store, 8B per row-quad per thread
        #pragma unroll
        for (int rr = 0; rr < 4; ++rr) {
            int row = rowBase + rg * 4 + rr;
            if (row < nN) {
                float4 a = (rr == 0) ? a0 : (rr == 1) ? a1 : (rr == 2) ? a2 : a3;
                union { __half2 h2[2]; uint2 u; } cv;
                cv.h2[0] = __floats2half2_rn(a.x, a.y);
                cv.h2[1] = __floats2half2_rn(a.z, a.w);
                *(uint2*)&Yh[(size_t)row * NFEAT + cx * 4] = cv.u;
            }
        }
    }
}

// ---------------- edge aggregation: one wave per node, 2 edges in flight per half ----
// out[i] = relu( sum_{e: dst=i} hg[src_e]*dinv[src_e]*dinv[i] + hg[i]*dinv[i]^2 + b )
__global__ __launch_bounds__(256) void k_agg(const __half* __restrict__ hg,
                                             const float* __restrict__ dinv,
                                             const int* __restrict__ off,
                                             const int* __restrict__ csr,
                                             const float* __restrict__ bias,
                                             float* __restrict__ out, int nN) {
    int node = (blockIdx.x * blockDim.x + threadIdx.x) >> 6;
    int lane = threadIdx.x & 63;
    if (node >= nN) return;
    const int half = lane >> 5;     // 0: even edges, 1: odd edges
    const int li   = lane & 31;     // features li*4 .. +3
    const float di = dinv[node];
    float4 acc = make_float4(0.f, 0.f, 0.f, 0.f);
    const int j0 = off[node], j1 = off[node + 1];

    // 2-deep software pipeline per half: next (csr, dinv, row) issued before current consumed
    int j = j0 + half;
    bool v = j < j1;
    int s = v ? csr[j] : 0;
    float w = v ? dinv[s] * di : 0.f;
    uint2 u = v ? *(const uint2*)&hg[(size_t)s * NFEAT + li * 4] : make_uint2(0u, 0u);
    while (v) {
        int jn = j + 2;
        bool vn = jn < j1;
        int sn = vn ? csr[jn] : 0;
        float wn = vn ? dinv[sn] * di : 0.f;
        uint2 un = vn ? *(const uint2*)&hg[(size_t)sn * NFEAT + li * 4] : make_uint2(0u, 0u);
        float2 f0 = __half22float2(*(__half2*)&u.x);
        float2 f1 = __half22float2(*(__half2*)&u.y);
        acc.x = fmaf(f0.x, w, acc.x);
        acc.y = fmaf(f0.y, w, acc.y);
        acc.z = fmaf(f1.x, w, acc.z);
        acc.w = fmaf(f1.y, w, acc.w);
        j = jn; v = vn; s = sn; w = wn; u = un;
    }
    // combine the two halves
    acc.x += __shfl_xor(acc.x, 32, 64);
    acc.y += __shfl_xor(acc.y, 32, 64);
    acc.z += __shfl_xor(acc.z, 32, 64);
    acc.w += __shfl_xor(acc.w, 32, 64);
    if (half == 0) {
        // self loop
        uint2 us = *(const uint2*)&hg[(size_t)node * NFEAT + li * 4];
        float2 g0 = __half22float2(*(__half2*)&us.x);
        float2 g1 = __half22float2(*(__half2*)&us.y);
        float ws = di * di;
        acc.x = fmaf(g0.x, ws, acc.x);
        acc.y = fmaf(g0.y, ws, acc.y);
        acc.z = fmaf(g1.x, ws, acc.z);
        acc.w = fmaf(g1.y, ws, acc.w);
        float4 bv = *(const float4*)&bias[li * 4];
        acc.x = fmaxf(acc.x + bv.x, 0.f);
        acc.y = fmaxf(acc.y + bv.y, 0.f);
        acc.z = fmaxf(acc.z + bv.z, 0.f);
        acc.w = fmaxf(acc.w + bv.w, 0.f);
        *(float4*)&out[(size_t)node * NFEAT + li * 4] = acc;
    }
}

// ---------------- mean pool over sorted batch ----------------
__global__ void k_pool(const float* __restrict__ h, const int* __restrict__ batch,
                       float* __restrict__ pooled, float* __restrict__ counts, int nN) {
    const int CHUNK = 128;
    int start = blockIdx.x * CHUNK;
    if (start >= nN) return;
    int end = min(start + CHUNK, nN);
    int f = threadIdx.x;  // 128 threads = 128 features
    float sum = 0.f;
    int cnt = 0;
    int cur = batch[start];
    for (int i = start; i < end; ++i) {
        int g = batch[i];
        if (g != cur) {
            atomicAdd(&pooled[cur * NFEAT + f], sum);
            if (f == 0) atomicAdd(&counts[cur], (float)cnt);
            sum = 0.f; cnt = 0; cur = g;
        }
        sum += h[(size_t)i * NFEAT + f];
        cnt++;
    }
    atomicAdd(&pooled[cur * NFEAT + f], sum);
    if (f == 0) atomicAdd(&counts[cur], (float)cnt);
}

// ---------------- classifier head: out[64,2] ----------------
__global__ void k_final(const float* __restrict__ pooled, const float* __restrict__ counts,
                        const float* __restrict__ Wc, const float* __restrict__ bc,
                        float* __restrict__ out) {
    int t = threadIdx.x;  // 128 threads: g = t>>1, class = t&1
    int g = t >> 1, c = t & 1;
    float inv = 1.0f / fmaxf(counts[g], 1.0f);
    float s = 0.f;
    for (int f = 0; f < NFEAT; ++f) s += pooled[g * NFEAT + f] * Wc[f * 2 + c];
    out[t] = s * inv + bc[c];
}

extern "C" void kernel_launch(void* const* d_in, const int* in_sizes, int n_in,
                              void* d_out, int out_size, void* d_ws, size_t ws_size,
                              hipStream_t stream) {
    const float* x   = (const float*)d_in[0];
    const int*   ei  = (const int*)d_in[1];
    const int*   bat = (const int*)d_in[2];
    const float* W1  = (const float*)d_in[3];
    const float* b1  = (const float*)d_in[4];
    const float* W2  = (const float*)d_in[5];
    const float* b2  = (const float*)d_in[6];
    const float* Wc  = (const float*)d_in[7];
    const float* bc  = (const float*)d_in[8];
    float* out = (float*)d_out;

    const int nN = in_sizes[0] / NFEAT;      // 50000
    const int nE = in_sizes[1] / 2;          // 800000
    const int* src = ei;
    const int* dst = ei + nE;

    char* ws = (char*)d_ws;
    size_t o = 0;
    auto alloc = [&](size_t bytes) -> char* {
        char* p = ws + o;
        o = (o + bytes + 255) & ~(size_t)255;
        return p;
    };
    // ---- zeroed region (one memset) ----
    unsigned int* cnt    = (unsigned int*)alloc((size_t)nN * 4);
    unsigned int* cursor = (unsigned int*)alloc((size_t)nN * 4);
    float* pooled        = (float*)alloc((size_t)NGRAPH * NFEAT * 4);
    float* counts        = (float*)alloc((size_t)NGRAPH * 4);
    size_t zero_bytes = o;
    // ---- rest ----
    int* off           = (int*)alloc(((size_t)nN + 1) * 4);
    unsigned int* bsum = (unsigned int*)alloc(256 * 4);
    unsigned int* boff = (unsigned int*)alloc(256 * 4);
    int* csr           = (int*)alloc((size_t)nE * 4);
    float* dinv        = (float*)alloc((size_t)nN * 4);
    __half* hg         = (__half*)alloc((size_t)nN * NFEAT * 2);  // fp16 gather operand
    float* hf          = (float*)alloc((size_t)nN * NFEAT * 4);   // fp32 activations
    (void)ws_size; (void)n_in; (void)out_size;

    hipMemsetAsync(d_ws, 0, zero_bytes, stream);

    const int nb = (nN + 255) / 256;  // scan blocks

    k_deg<<<(nE + 255) / 256, 256, 0, stream>>>(dst, cnt, nE);
    k_dinv<<<(nN + 255) / 256, 256, 0, stream>>>(cnt, dinv, nN);
    k_scan1<<<nb, 256, 0, stream>>>(cnt, bsum, nN);
    k_scan2<<<1, 256, 0, stream>>>(bsum, boff, off, nb, nN);
    k_scan3<<<nb, 256, 0, stream>>>(cnt, boff, off, nN);
    k_scatter<<<(nE + 255) / 256, 256, 0, stream>>>(src, dst, off, cursor, csr, nE);

    const int gemmGrid = (nN + 32 * 3 - 1) / (32 * 3);  // 3 chunks/block, zero imbalance at 50000

    // layer 1: hg = fp16(x @ W1) ; hf = relu(agg(hg) + b1)
    k_gemm<<<gemmGrid, 256, 0, stream>>>(x, W1, hg, nN);
    k_agg<<<(nN + 3) / 4, 256, 0, stream>>>(hg, dinv, off, csr, b1, hf, nN);
    // layer 2: hg = fp16(hf @ W2) ; hf = relu(agg(hg) + b2)
    k_gemm<<<gemmGrid, 256, 0, stream>>>(hf, W2, hg, nN);
    k_agg<<<(nN + 3) / 4, 256, 0, stream>>>(hg, dinv, off, csr, b2, hf, nN);

    // mean pool + head
    k_pool<<<(nN + 127) / 128, 128, 0, stream>>>(hf, bat, pooled, counts, nN);
    k_final<<<1, 128, 0, stream>>>(pooled, counts, Wc, bc, out);
}

// Round 6
// 332.081 us; speedup vs baseline: 1.4561x; 1.2959x over previous
//
#include <hip/hip_runtime.h>
#include <hip/hip_fp16.h>

#define NFEAT 128
#define NGRAPH 64

// ---------------- degree histogram ----------------
__global__ void k_deg(const int* __restrict__ dst, unsigned int* __restrict__ cnt, int nE) {
    int e = blockIdx.x * blockDim.x + threadIdx.x;
    if (e < nE) atomicAdd(&cnt[dst[e]], 1u);
}

// ---------------- scan stage 1 (+ fused dinv) ----------------
__global__ void k_scan1(const unsigned int* __restrict__ cnt, unsigned int* __restrict__ bsum,
                        float* __restrict__ dinv, int nN) {
    __shared__ unsigned int ws[4];
    int i = blockIdx.x * 256 + threadIdx.x;
    unsigned int v = (i < nN) ? cnt[i] : 0u;
    if (i < nN) dinv[i] = 1.0f / sqrtf((float)(v + 1u));  // deg incl. self loop >= 1
    unsigned int r = v;
    for (int d = 32; d; d >>= 1) r += __shfl_down(r, d, 64);
    if ((threadIdx.x & 63) == 0) ws[threadIdx.x >> 6] = r;
    __syncthreads();
    if (threadIdx.x == 0) bsum[blockIdx.x] = ws[0] + ws[1] + ws[2] + ws[3];
}

__global__ void k_scan2(const unsigned int* __restrict__ bsum, unsigned int* __restrict__ boff,
                        int* __restrict__ off, int nb, int nN) {
    __shared__ unsigned int ws[4];
    int t = threadIdx.x;
    unsigned int v = (t < nb) ? bsum[t] : 0u;
    unsigned int s = v;
    for (int d = 1; d < 64; d <<= 1) {
        unsigned int u = __shfl_up(s, d, 64);
        if ((t & 63) >= d) s += u;
    }
    int w = t >> 6;
    if ((t & 63) == 63) ws[w] = s;
    __syncthreads();
    unsigned int woff = 0;
    for (int j = 0; j < w; ++j) woff += ws[j];
    unsigned int excl = woff + s - v;
    if (t < nb) boff[t] = excl;
    if (t == nb - 1) off[nN] = (int)(excl + v);
}

__global__ void k_scan3(const unsigned int* __restrict__ cnt, const unsigned int* __restrict__ boff,
                        int* __restrict__ off, int nN) {
    __shared__ unsigned int ws[4];
    int i = blockIdx.x * 256 + threadIdx.x;
    int t = threadIdx.x;
    unsigned int v = (i < nN) ? cnt[i] : 0u;
    unsigned int s = v;
    for (int d = 1; d < 64; d <<= 1) {
        unsigned int u = __shfl_up(s, d, 64);
        if ((t & 63) >= d) s += u;
    }
    int w = t >> 6;
    if ((t & 63) == 63) ws[w] = s;
    __syncthreads();
    unsigned int woff = 0;
    for (int j = 0; j < w; ++j) woff += ws[j];
    if (i < nN) off[i] = (int)(boff[blockIdx.x] + woff + s - v);
}

// ---------------- CSR scatter: (src, norm) pairs grouped by dst ----------------
__global__ void k_scatter(const int* __restrict__ src, const int* __restrict__ dst,
                          const int* __restrict__ off, unsigned int* __restrict__ cursor,
                          const float* __restrict__ dinv, int2* __restrict__ epair, int nE) {
    int e = blockIdx.x * blockDim.x + threadIdx.x;
    if (e >= nE) return;
    int s = src[e], d = dst[e];
    int pos = off[d] + (int)atomicAdd(&cursor[d], 1u);
    float w = dinv[s] * dinv[d];
    epair[pos] = make_int2(s, __float_as_int(w));
}

// ---------------- dense GEMM: Yh[n,128](fp16) = X[n,128] @ W[128,128] ----------------
// 48 KB LDS (sW in two 64-row halves) -> 3 blocks/CU. 32 rows/chunk, 4x4 per thread.
__global__ __launch_bounds__(256) void k_gemm(const float* __restrict__ X,
                                              const float* __restrict__ W,
                                              __half* __restrict__ Yh, int nN) {
    __shared__ float sW[64 * NFEAT];      // 32 KB (one k-half)
    __shared__ float sX[32 * NFEAT];      // 16 KB
    const int cx = threadIdx.x & 31;      // cols cx*4 .. +3
    const int rg = threadIdx.x >> 5;      // row group: rows rg*4 .. +3
    for (int rowBase = blockIdx.x * 32; rowBase < nN; rowBase += gridDim.x * 32) {
        __syncthreads();  // previous chunk's consumers done before sX overwrite
        #pragma unroll
        for (int rr = 0; rr < 4; ++rr) {
            int r = rg + rr * 8;
            int row = rowBase + r;
            float4 v = make_float4(0.f, 0.f, 0.f, 0.f);
            if (row < nN) v = *(const float4*)&X[(size_t)row * NFEAT + cx * 4];
            *(float4*)&sX[r * NFEAT + cx * 4] = v;
        }
        float4 a0 = make_float4(0.f,0.f,0.f,0.f), a1 = a0, a2 = a0, a3 = a0;
        for (int kk = 0; kk < NFEAT; kk += 64) {
            __syncthreads();  // sX ready / previous half's consumers done
            #pragma unroll
            for (int q = 0; q < 8; ++q) {  // stage 64x128 W-half: 8 float4 per thread
                int idx = (q * 256 + threadIdx.x) * 4;
                *(float4*)&sW[idx] = *(const float4*)&W[(size_t)kk * NFEAT + idx];
            }
            __syncthreads();
            #pragma unroll 2
            for (int k = 0; k < 64; k += 4) {
                float4 x0 = *(const float4*)&sX[(rg * 4 + 0) * NFEAT + kk + k];
                float4 x1 = *(const float4*)&sX[(rg * 4 + 1) * NFEAT + kk + k];
                float4 x2 = *(const float4*)&sX[(rg * 4 + 2) * NFEAT + kk + k];
                float4 x3 = *(const float4*)&sX[(rg * 4 + 3) * NFEAT + kk + k];
                #pragma unroll
                for (int i = 0; i < 4; ++i) {
                    float4 wv = *(const float4*)&sW[(k + i) * NFEAT + cx * 4];
                    float s0 = ((const float*)&x0)[i];
                    float s1 = ((const float*)&x1)[i];
                    float s2 = ((const float*)&x2)[i];
                    float s3 = ((const float*)&x3)[i];
                    a0.x = fmaf(s0, wv.x, a0.x); a0.y = fmaf(s0, wv.y, a0.y);
                    a0.z = fmaf(s0, wv.z, a0.z); a0.w = fmaf(s0, wv.w, a0.w);
                    a1.x = fmaf(s1, wv.x, a1.x); a1.y = fmaf(s1, wv.y, a1.y);
                    a1.z = fmaf(s1, wv.z, a1.z); a1.w = fmaf(s1, wv.w, a1.w);
                    a2.x = fmaf(s2, wv.x, a2.x); a2.y = fmaf(s2, wv.y, a2.y);
                    a2.z = fmaf(s2, wv.z, a2.z); a2.w = fmaf(s2, wv.w, a2.w);
                    a3.x = fmaf(s3, wv.x, a3.x); a3.y = fmaf(s3, wv.y, a3.y);
                    a3.z = fmaf(s3, wv.z, a3.z); a3.w = fmaf(s3, wv.w, a3.w);
                }
            }
        }
        #pragma unroll
        for (int rr = 0; rr < 4; ++rr) {
            int row = rowBase + rg * 4 + rr;
            if (row < nN) {
                float4 a = (rr == 0) ? a0 : (rr == 1) ? a1 : (rr == 2) ? a2 : a3;
                union { __half2 h2[2]; uint2 u; } cv;
                cv.h2[0] = __floats2half2_rn(a.x, a.y);
                cv.h2[1] = __floats2half2_rn(a.z, a.w);
                *(uint2*)&Yh[(size_t)row * NFEAT + cx * 4] = cv.u;
            }
        }
    }
}

// ---------------- edge aggregation: 1 node/wave, 4 groups x 16 lanes ----------------
// 3-stage rotation: each iteration issues an independent row-load + pair-load.
// out[i] = relu( sum_e hg[src_e]*norm_e + hg[i]*dinv[i]^2 + b )
__global__ __launch_bounds__(256) void k_agg(const __half* __restrict__ hg,
                                             const float* __restrict__ dinv,
                                             const int* __restrict__ off,
                                             const int2* __restrict__ epair,
                                             const float* __restrict__ bias,
                                             float* __restrict__ out, int nN) {
    int node = (blockIdx.x * blockDim.x + threadIdx.x) >> 6;
    int lane = threadIdx.x & 63;
    if (node >= nN) return;
    const int grp = lane >> 4;      // 4 edge streams
    const int li  = lane & 15;      // features li*8 .. +7 (uint4 of 8 fp16)
    const float di = dinv[node];    // independent broadcast load, used at end
    const uint4 us = *(const uint4*)&hg[(size_t)node * NFEAT + li * 8];  // self row, issued early
    const int j0 = off[node], j1 = off[node + 1];

    float4 acc0 = make_float4(0.f,0.f,0.f,0.f), acc1 = acc0;

    // 3-stage pipeline: u=row(current), p=pair(current), pn=pair(next)
    int j = j0 + grp;
    bool v = j < j1;
    int2 p = v ? epair[j] : make_int2(0, 0);
    uint4 u = v ? *(const uint4*)&hg[(size_t)p.x * NFEAT + li * 8] : make_uint4(0u,0u,0u,0u);
    int jn = j + 4;
    bool vn = vn = jn < j1;
    int2 pn = vn ? epair[jn] : make_int2(0, 0);
    while (v) {
        // issue next row (from pn) and next-next pair — both independent of current FMAs
        uint4 un = vn ? *(const uint4*)&hg[(size_t)pn.x * NFEAT + li * 8] : make_uint4(0u,0u,0u,0u);
        int jnn = jn + 4;
        bool vnn = jnn < j1;
        int2 pnn = vnn ? epair[jnn] : make_int2(0, 0);
        float w = __int_as_float(p.y);
        float2 f0 = __half22float2(*(__half2*)&u.x);
        float2 f1 = __half22float2(*(__half2*)&u.y);
        float2 f2 = __half22float2(*(__half2*)&u.z);
        float2 f3 = __half22float2(*(__half2*)&u.w);
        acc0.x = fmaf(f0.x, w, acc0.x); acc0.y = fmaf(f0.y, w, acc0.y);
        acc0.z = fmaf(f1.x, w, acc0.z); acc0.w = fmaf(f1.y, w, acc0.w);
        acc1.x = fmaf(f2.x, w, acc1.x); acc1.y = fmaf(f2.y, w, acc1.y);
        acc1.z = fmaf(f3.x, w, acc1.z); acc1.w = fmaf(f3.y, w, acc1.w);
        u = un; p = pn; pn = pnn; v = vn; vn = vnn; j = jn; jn = jnn;
    }
    // reduce across the 4 groups (lanes l, l^16, l^32, l^48)
    acc0.x += __shfl_xor(acc0.x, 16, 64); acc0.y += __shfl_xor(acc0.y, 16, 64);
    acc0.z += __shfl_xor(acc0.z, 16, 64); acc0.w += __shfl_xor(acc0.w, 16, 64);
    acc1.x += __shfl_xor(acc1.x, 16, 64); acc1.y += __shfl_xor(acc1.y, 16, 64);
    acc1.z += __shfl_xor(acc1.z, 16, 64); acc1.w += __shfl_xor(acc1.w, 16, 64);
    acc0.x += __shfl_xor(acc0.x, 32, 64); acc0.y += __shfl_xor(acc0.y, 32, 64);
    acc0.z += __shfl_xor(acc0.z, 32, 64); acc0.w += __shfl_xor(acc0.w, 32, 64);
    acc1.x += __shfl_xor(acc1.x, 32, 64); acc1.y += __shfl_xor(acc1.y, 32, 64);
    acc1.z += __shfl_xor(acc1.z, 32, 64); acc1.w += __shfl_xor(acc1.w, 32, 64);
    if (grp == 0) {
        float ws = di * di;
        float2 g0 = __half22float2(*(__half2*)&us.x);
        float2 g1 = __half22float2(*(__half2*)&us.y);
        float2 g2 = __half22float2(*(__half2*)&us.z);
        float2 g3 = __half22float2(*(__half2*)&us.w);
        acc0.x = fmaf(g0.x, ws, acc0.x); acc0.y = fmaf(g0.y, ws, acc0.y);
        acc0.z = fmaf(g1.x, ws, acc0.z); acc0.w = fmaf(g1.y, ws, acc0.w);
        acc1.x = fmaf(g2.x, ws, acc1.x); acc1.y = fmaf(g2.y, ws, acc1.y);
        acc1.z = fmaf(g3.x, ws, acc1.z); acc1.w = fmaf(g3.y, ws, acc1.w);
        float4 b0 = *(const float4*)&bias[li * 8];
        float4 b1 = *(const float4*)&bias[li * 8 + 4];
        acc0.x = fmaxf(acc0.x + b0.x, 0.f); acc0.y = fmaxf(acc0.y + b0.y, 0.f);
        acc0.z = fmaxf(acc0.z + b0.z, 0.f); acc0.w = fmaxf(acc0.w + b0.w, 0.f);
        acc1.x = fmaxf(acc1.x + b1.x, 0.f); acc1.y = fmaxf(acc1.y + b1.y, 0.f);
        acc1.z = fmaxf(acc1.z + b1.z, 0.f); acc1.w = fmaxf(acc1.w + b1.w, 0.f);
        *(float4*)&out[(size_t)node * NFEAT + li * 8] = acc0;
        *(float4*)&out[(size_t)node * NFEAT + li * 8 + 4] = acc1;
    }
}

// ---------------- mean pool: 64-row chunks, 2 row streams / block ----------------
__global__ void k_pool(const float* __restrict__ h, const int* __restrict__ batch,
                       float* __restrict__ pooled, float* __restrict__ counts, int nN) {
    const int CHUNK = 64;
    int start = blockIdx.x * CHUNK;
    if (start >= nN) return;
    int end = min(start + CHUNK, nN);
    int f = threadIdx.x & 127;
    int sub = threadIdx.x >> 7;   // 2 interleaved streams
    float sum = 0.f;
    int cnt = 0;
    int cur = -1;
    for (int i = start + sub; i < end; i += 2) {
        int g = batch[i];
        if (g != cur) {
            if (cur >= 0) {
                atomicAdd(&pooled[cur * NFEAT + f], sum);
                if (f == 0) atomicAdd(&counts[cur], (float)cnt);
            }
            sum = 0.f; cnt = 0; cur = g;
        }
        sum += h[(size_t)i * NFEAT + f];
        cnt++;
    }
    if (cur >= 0) {
        atomicAdd(&pooled[cur * NFEAT + f], sum);
        if (f == 0) atomicAdd(&counts[cur], (float)cnt);
    }
}

// ---------------- classifier head: out[64,2] ----------------
__global__ void k_final(const float* __restrict__ pooled, const float* __restrict__ counts,
                        const float* __restrict__ Wc, const float* __restrict__ bc,
                        float* __restrict__ out) {
    int t = threadIdx.x;  // g = t>>1, class = t&1
    int g = t >> 1, c = t & 1;
    float inv = 1.0f / fmaxf(counts[g], 1.0f);
    float s = 0.f;
    for (int f = 0; f < NFEAT; ++f) s += pooled[g * NFEAT + f] * Wc[f * 2 + c];
    out[t] = s * inv + bc[c];
}

extern "C" void kernel_launch(void* const* d_in, const int* in_sizes, int n_in,
                              void* d_out, int out_size, void* d_ws, size_t ws_size,
                              hipStream_t stream) {
    const float* x   = (const float*)d_in[0];
    const int*   ei  = (const int*)d_in[1];
    const int*   bat = (const int*)d_in[2];
    const float* W1  = (const float*)d_in[3];
    const float* b1  = (const float*)d_in[4];
    const float* W2  = (const float*)d_in[5];
    const float* b2  = (const float*)d_in[6];
    const float* Wc  = (const float*)d_in[7];
    const float* bc  = (const float*)d_in[8];
    float* out = (float*)d_out;

    const int nN = in_sizes[0] / NFEAT;      // 50000
    const int nE = in_sizes[1] / 2;          // 800000
    const int* src = ei;
    const int* dst = ei + nE;

    char* ws = (char*)d_ws;
    size_t o = 0;
    auto alloc = [&](size_t bytes) -> char* {
        char* p = ws + o;
        o = (o + bytes + 255) & ~(size_t)255;
        return p;
    };
    // ---- zeroed region (one memset) ----
    unsigned int* cnt    = (unsigned int*)alloc((size_t)nN * 4);
    unsigned int* cursor = (unsigned int*)alloc((size_t)nN * 4);
    float* pooled        = (float*)alloc((size_t)NGRAPH * NFEAT * 4);
    float* counts        = (float*)alloc((size_t)NGRAPH * 4);
    size_t zero_bytes = o;
    // ---- rest ----
    int* off           = (int*)alloc(((size_t)nN + 1) * 4);
    unsigned int* bsum = (unsigned int*)alloc(256 * 4);
    unsigned int* boff = (unsigned int*)alloc(256 * 4);
    int2* epair        = (int2*)alloc((size_t)nE * 8);            // (src, norm) per edge
    float* dinv        = (float*)alloc((size_t)nN * 4);
    __half* hg         = (__half*)alloc((size_t)nN * NFEAT * 2);  // fp16 gather operand
    float* hf          = (float*)alloc((size_t)nN * NFEAT * 4);   // fp32 activations
    (void)ws_size; (void)n_in; (void)out_size;

    hipMemsetAsync(d_ws, 0, zero_bytes, stream);

    const int nb = (nN + 255) / 256;  // scan blocks

    k_deg<<<(nE + 255) / 256, 256, 0, stream>>>(dst, cnt, nE);
    k_scan1<<<nb, 256, 0, stream>>>(cnt, bsum, dinv, nN);
    k_scan2<<<1, 256, 0, stream>>>(bsum, boff, off, nb, nN);
    k_scan3<<<nb, 256, 0, stream>>>(cnt, boff, off, nN);
    k_scatter<<<(nE + 255) / 256, 256, 0, stream>>>(src, dst, off, cursor, dinv, epair, nE);

    const int gemmGrid = 782;  // 2 chunks of 32 rows per block; 3 blocks/CU at 48 KB LDS

    // layer 1: hg = fp16(x @ W1) ; hf = relu(agg(hg) + b1)
    k_gemm<<<gemmGrid, 256, 0, stream>>>(x, W1, hg, nN);
    k_agg<<<(nN + 3) / 4, 256, 0, stream>>>(hg, dinv, off, epair, b1, hf, nN);
    // layer 2: hg = fp16(hf @ W2) ; hf = relu(agg(hg) + b2)
    k_gemm<<<gemmGrid, 256, 0, stream>>>(hf, W2, hg, nN);
    k_agg<<<(nN + 3) / 4, 256, 0, stream>>>(hg, dinv, off, epair, b2, hf, nN);

    // mean pool + head
    k_pool<<<(nN + 63) / 64, 256, 0, stream>>>(hf, bat, pooled, counts, nN);
    k_final<<<1, 128, 0, stream>>>(pooled, counts, Wc, bc, out);
}

// Round 7
// 304.277 us; speedup vs baseline: 1.5891x; 1.0914x over previous
//
#include <hip/hip_runtime.h>
#include <hip/hip_fp16.h>

#define NFEAT 128
#define NGRAPH 64

typedef _Float16 f16x8 __attribute__((ext_vector_type(8)));
typedef float f32x4 __attribute__((ext_vector_type(4)));

// ---------------- degree histogram ----------------
__global__ void k_deg(const int* __restrict__ dst, unsigned int* __restrict__ cnt, int nE) {
    int e = blockIdx.x * blockDim.x + threadIdx.x;
    if (e < nE) atomicAdd(&cnt[dst[e]], 1u);
}

// ---------------- scan stage 1 (+ fused dinv) ----------------
__global__ void k_scan1(const unsigned int* __restrict__ cnt, unsigned int* __restrict__ bsum,
                        float* __restrict__ dinv, int nN) {
    __shared__ unsigned int ws[4];
    int i = blockIdx.x * 256 + threadIdx.x;
    unsigned int v = (i < nN) ? cnt[i] : 0u;
    if (i < nN) dinv[i] = 1.0f / sqrtf((float)(v + 1u));  // deg incl. self loop >= 1
    unsigned int r = v;
    for (int d = 32; d; d >>= 1) r += __shfl_down(r, d, 64);
    if ((threadIdx.x & 63) == 0) ws[threadIdx.x >> 6] = r;
    __syncthreads();
    if (threadIdx.x == 0) bsum[blockIdx.x] = ws[0] + ws[1] + ws[2] + ws[3];
}

__global__ void k_scan2(const unsigned int* __restrict__ bsum, unsigned int* __restrict__ boff,
                        int* __restrict__ off, int nb, int nN) {
    __shared__ unsigned int ws[4];
    int t = threadIdx.x;
    unsigned int v = (t < nb) ? bsum[t] : 0u;
    unsigned int s = v;
    for (int d = 1; d < 64; d <<= 1) {
        unsigned int u = __shfl_up(s, d, 64);
        if ((t & 63) >= d) s += u;
    }
    int w = t >> 6;
    if ((t & 63) == 63) ws[w] = s;
    __syncthreads();
    unsigned int woff = 0;
    for (int j = 0; j < w; ++j) woff += ws[j];
    unsigned int excl = woff + s - v;
    if (t < nb) boff[t] = excl;
    if (t == nb - 1) off[nN] = (int)(excl + v);
}

__global__ void k_scan3(const unsigned int* __restrict__ cnt, const unsigned int* __restrict__ boff,
                        int* __restrict__ off, int nN) {
    __shared__ unsigned int ws[4];
    int i = blockIdx.x * 256 + threadIdx.x;
    int t = threadIdx.x;
    unsigned int v = (i < nN) ? cnt[i] : 0u;
    unsigned int s = v;
    for (int d = 1; d < 64; d <<= 1) {
        unsigned int u = __shfl_up(s, d, 64);
        if ((t & 63) >= d) s += u;
    }
    int w = t >> 6;
    if ((t & 63) == 63) ws[w] = s;
    __syncthreads();
    unsigned int woff = 0;
    for (int j = 0; j < w; ++j) woff += ws[j];
    if (i < nN) off[i] = (int)(boff[blockIdx.x] + woff + s - v);
}

// ---------------- CSR scatter: (src, norm) pairs grouped by dst ----------------
__global__ void k_scatter(const int* __restrict__ src, const int* __restrict__ dst,
                          const int* __restrict__ off, unsigned int* __restrict__ cursor,
                          const float* __restrict__ dinv, int2* __restrict__ epair, int nE) {
    int e = blockIdx.x * blockDim.x + threadIdx.x;
    if (e >= nE) return;
    int s = src[e], d = dst[e];
    int pos = off[d] + (int)atomicAdd(&cursor[d], 1u);
    float w = dinv[s] * dinv[d];
    epair[pos] = make_int2(s, __float_as_int(w));
}

// ---------------- MFMA GEMM: Yh[n,128](fp16) = X[n,128] @ W[128,128] ----------------
// fp16 operands, fp32 accum via v_mfma_f32_16x16x32_f16.
// Block = 4 waves; wave w owns cols [w*32, w*32+32). B-frags (W^T) live in VGPRs for
// the whole kernel. Per 64-row chunk: stage X as fp16 in LDS, 4 row-tiles of 16.
// D^T trick: mfma(b, a) -> lane holds one X-row (col=lane&15 of D) and 4 consecutive
// output features (row=(lane>>4)*4+reg, verified dtype-independent C/D layout).
template <typename IN>
__global__ __launch_bounds__(256) void k_gemm(const IN* __restrict__ X,
                                              const float* __restrict__ W,
                                              __half* __restrict__ Yh, int nN) {
    const int PAD = 136;  // +8 fp16 pad: row stride 272B = 68 words -> 2-way-max bank aliasing
    __shared__ __align__(16) _Float16 sWt[NFEAT * PAD];  // W^T, 34.8 KB
    __shared__ __align__(16) _Float16 sX[64 * PAD];      // 17.4 KB
    const int t = threadIdx.x;
    // ---- transpose W (fp32 row-major [k][n]) -> sWt fp16 [n][k], once per block ----
    {
        int n4 = (t & 31) * 4;
        #pragma unroll
        for (int it = 0; it < 16; ++it) {
            int k = (t >> 5) + it * 8;
            float4 wv = *(const float4*)&W[(size_t)k * NFEAT + n4];
            sWt[(n4 + 0) * PAD + k] = (_Float16)wv.x;
            sWt[(n4 + 1) * PAD + k] = (_Float16)wv.y;
            sWt[(n4 + 2) * PAD + k] = (_Float16)wv.z;
            sWt[(n4 + 3) * PAD + k] = (_Float16)wv.w;
        }
    }
    __syncthreads();
    const int wv = t >> 6;                 // wave id: cols wv*32..+31
    const int lane = t & 63;
    const int l16 = lane & 15, lh = lane >> 4;
    // ---- B fragments: n = wv*32 + nt*16 + l16, k = kk*32 + lh*8 + [0..7] ----
    f16x8 bfr[2][4];
    #pragma unroll
    for (int nt = 0; nt < 2; ++nt)
        #pragma unroll
        for (int kk = 0; kk < 4; ++kk) {
            int n = wv * 32 + nt * 16 + l16;
            bfr[nt][kk] = *(const f16x8*)&sWt[n * PAD + kk * 32 + lh * 8];
        }
    for (int rowBase = blockIdx.x * 64; rowBase < nN; rowBase += gridDim.x * 64) {
        __syncthreads();  // previous chunk's readers done before sX overwrite
        if constexpr (sizeof(IN) == 4) {
            #pragma unroll
            for (int it = 0; it < 8; ++it) {
                int idx = it * 1024 + t * 4;
                int r = idx >> 7, c = idx & 127;
                int row = rowBase + r;
                float4 v = (row < nN) ? *(const float4*)&X[(size_t)row * NFEAT + c]
                                      : make_float4(0.f, 0.f, 0.f, 0.f);
                _Float16 h4[4] = {(_Float16)v.x, (_Float16)v.y, (_Float16)v.z, (_Float16)v.w};
                *(uint2*)&sX[r * PAD + c] = *(uint2*)h4;
            }
        } else {
            #pragma unroll
            for (int it = 0; it < 4; ++it) {
                int idx = it * 2048 + t * 8;
                int r = idx >> 7, c = idx & 127;
                int row = rowBase + r;
                uint4 v = (row < nN) ? *(const uint4*)&X[(size_t)row * NFEAT + c]
                                     : make_uint4(0u, 0u, 0u, 0u);
                *(uint4*)&sX[r * PAD + c] = v;
            }
        }
        __syncthreads();
        #pragma unroll
        for (int rt = 0; rt < 4; ++rt) {
            f16x8 a[4];
            #pragma unroll
            for (int kk = 0; kk < 4; ++kk)
                a[kk] = *(const f16x8*)&sX[(rt * 16 + l16) * PAD + kk * 32 + lh * 8];
            int row = rowBase + rt * 16 + l16;
            #pragma unroll
            for (int nt = 0; nt < 2; ++nt) {
                f32x4 acc = {0.f, 0.f, 0.f, 0.f};
                #pragma unroll
                for (int kk = 0; kk < 4; ++kk)
                    acc = __builtin_amdgcn_mfma_f32_16x16x32_f16(bfr[nt][kk], a[kk], acc, 0, 0, 0);
                if (row < nN) {
                    __half2 p0 = __floats2half2_rn(acc[0], acc[1]);
                    __half2 p1 = __floats2half2_rn(acc[2], acc[3]);
                    uint2 st = make_uint2(*(unsigned*)&p0, *(unsigned*)&p1);
                    *(uint2*)&Yh[(size_t)row * NFEAT + wv * 32 + nt * 16 + lh * 4] = st;
                }
            }
        }
    }
}

// ---------------- edge aggregation: 1 node/wave, 8 streams x 8 lanes ----------------
// lane owns features li*16..+15 (two uint4 of fp16). 3-stage rotation keeps
// ~2 rows (4 b128 loads) + 2 pair loads in flight per stream.
__global__ __launch_bounds__(256) void k_agg(const __half* __restrict__ hg,
                                             const float* __restrict__ dinv,
                                             const int* __restrict__ off,
                                             const int2* __restrict__ epair,
                                             const float* __restrict__ bias,
                                             __half* __restrict__ out, int nN) {
    int node = (blockIdx.x * blockDim.x + threadIdx.x) >> 6;
    int lane = threadIdx.x & 63;
    if (node >= nN) return;
    const int grp = lane >> 3;      // 8 edge streams
    const int li  = lane & 7;       // feature slice li*16 .. +15
    const float di = dinv[node];
    const uint4 us0 = *(const uint4*)&hg[(size_t)node * NFEAT + li * 16];
    const uint4 us1 = *(const uint4*)&hg[(size_t)node * NFEAT + li * 16 + 8];
    const int j0 = off[node], j1 = off[node + 1];

    float4 A0 = make_float4(0.f,0.f,0.f,0.f), A1 = A0, A2 = A0, A3 = A0;

    int j = j0 + grp;
    bool v = j < j1;
    int2 p = v ? epair[j] : make_int2(0, 0);
    uint4 u0 = make_uint4(0u,0u,0u,0u), u1 = u0;
    if (v) {
        u0 = *(const uint4*)&hg[(size_t)p.x * NFEAT + li * 16];
        u1 = *(const uint4*)&hg[(size_t)p.x * NFEAT + li * 16 + 8];
    }
    int jn = j + 8;
    bool vn = jn < j1;
    int2 pn = vn ? epair[jn] : make_int2(0, 0);
    while (v) {
        uint4 un0 = make_uint4(0u,0u,0u,0u), un1 = un0;
        if (vn) {
            un0 = *(const uint4*)&hg[(size_t)pn.x * NFEAT + li * 16];
            un1 = *(const uint4*)&hg[(size_t)pn.x * NFEAT + li * 16 + 8];
        }
        int jnn = jn + 8;
        bool vnn = jnn < j1;
        int2 pnn = vnn ? epair[jnn] : make_int2(0, 0);
        float w = __int_as_float(p.y);
        float2 f0 = __half22float2(*(__half2*)&u0.x);
        float2 f1 = __half22float2(*(__half2*)&u0.y);
        float2 f2 = __half22float2(*(__half2*)&u0.z);
        float2 f3 = __half22float2(*(__half2*)&u0.w);
        float2 f4 = __half22float2(*(__half2*)&u1.x);
        float2 f5 = __half22float2(*(__half2*)&u1.y);
        float2 f6 = __half22float2(*(__half2*)&u1.z);
        float2 f7 = __half22float2(*(__half2*)&u1.w);
        A0.x = fmaf(f0.x, w, A0.x); A0.y = fmaf(f0.y, w, A0.y);
        A0.z = fmaf(f1.x, w, A0.z); A0.w = fmaf(f1.y, w, A0.w);
        A1.x = fmaf(f2.x, w, A1.x); A1.y = fmaf(f2.y, w, A1.y);
        A1.z = fmaf(f3.x, w, A1.z); A1.w = fmaf(f3.y, w, A1.w);
        A2.x = fmaf(f4.x, w, A2.x); A2.y = fmaf(f4.y, w, A2.y);
        A2.z = fmaf(f5.x, w, A2.z); A2.w = fmaf(f5.y, w, A2.w);
        A3.x = fmaf(f6.x, w, A3.x); A3.y = fmaf(f6.y, w, A3.y);
        A3.z = fmaf(f7.x, w, A3.z); A3.w = fmaf(f7.y, w, A3.w);
        u0 = un0; u1 = un1; p = pn; pn = pnn; v = vn; vn = vnn; j = jn; jn = jnn;
    }
    // reduce across the 8 streams (xor 8, 16, 32)
    #pragma unroll
    for (int d = 8; d < 64; d <<= 1) {
        A0.x += __shfl_xor(A0.x, d, 64); A0.y += __shfl_xor(A0.y, d, 64);
        A0.z += __shfl_xor(A0.z, d, 64); A0.w += __shfl_xor(A0.w, d, 64);
        A1.x += __shfl_xor(A1.x, d, 64); A1.y += __shfl_xor(A1.y, d, 64);
        A1.z += __shfl_xor(A1.z, d, 64); A1.w += __shfl_xor(A1.w, d, 64);
        A2.x += __shfl_xor(A2.x, d, 64); A2.y += __shfl_xor(A2.y, d, 64);
        A2.z += __shfl_xor(A2.z, d, 64); A2.w += __shfl_xor(A2.w, d, 64);
        A3.x += __shfl_xor(A3.x, d, 64); A3.y += __shfl_xor(A3.y, d, 64);
        A3.z += __shfl_xor(A3.z, d, 64); A3.w += __shfl_xor(A3.w, d, 64);
    }
    if (grp == 0) {
        float ws = di * di;
        float2 g0 = __half22float2(*(__half2*)&us0.x);
        float2 g1 = __half22float2(*(__half2*)&us0.y);
        float2 g2 = __half22float2(*(__half2*)&us0.z);
        float2 g3 = __half22float2(*(__half2*)&us0.w);
        float2 g4 = __half22float2(*(__half2*)&us1.x);
        float2 g5 = __half22float2(*(__half2*)&us1.y);
        float2 g6 = __half22float2(*(__half2*)&us1.z);
        float2 g7 = __half22float2(*(__half2*)&us1.w);
        A0.x = fmaf(g0.x, ws, A0.x); A0.y = fmaf(g0.y, ws, A0.y);
        A0.z = fmaf(g1.x, ws, A0.z); A0.w = fmaf(g1.y, ws, A0.w);
        A1.x = fmaf(g2.x, ws, A1.x); A1.y = fmaf(g2.y, ws, A1.y);
        A1.z = fmaf(g3.x, ws, A1.z); A1.w = fmaf(g3.y, ws, A1.w);
        A2.x = fmaf(g4.x, ws, A2.x); A2.y = fmaf(g4.y, ws, A2.y);
        A2.z = fmaf(g5.x, ws, A2.z); A2.w = fmaf(g5.y, ws, A2.w);
        A3.x = fmaf(g6.x, ws, A3.x); A3.y = fmaf(g6.y, ws, A3.y);
        A3.z = fmaf(g7.x, ws, A3.z); A3.w = fmaf(g7.y, ws, A3.w);
        const float4 b0 = *(const float4*)&bias[li * 16];
        const float4 b1 = *(const float4*)&bias[li * 16 + 4];
        const float4 b2 = *(const float4*)&bias[li * 16 + 8];
        const float4 b3 = *(const float4*)&bias[li * 16 + 12];
        A0.x = fmaxf(A0.x + b0.x, 0.f); A0.y = fmaxf(A0.y + b0.y, 0.f);
        A0.z = fmaxf(A0.z + b0.z, 0.f); A0.w = fmaxf(A0.w + b0.w, 0.f);
        A1.x = fmaxf(A1.x + b1.x, 0.f); A1.y = fmaxf(A1.y + b1.y, 0.f);
        A1.z = fmaxf(A1.z + b1.z, 0.f); A1.w = fmaxf(A1.w + b1.w, 0.f);
        A2.x = fmaxf(A2.x + b2.x, 0.f); A2.y = fmaxf(A2.y + b2.y, 0.f);
        A2.z = fmaxf(A2.z + b2.z, 0.f); A2.w = fmaxf(A2.w + b2.w, 0.f);
        A3.x = fmaxf(A3.x + b3.x, 0.f); A3.y = fmaxf(A3.y + b3.y, 0.f);
        A3.z = fmaxf(A3.z + b3.z, 0.f); A3.w = fmaxf(A3.w + b3.w, 0.f);
        __half2 h0 = __floats2half2_rn(A0.x, A0.y), h1 = __floats2half2_rn(A0.z, A0.w);
        __half2 h2 = __floats2half2_rn(A1.x, A1.y), h3 = __floats2half2_rn(A1.z, A1.w);
        __half2 h4 = __floats2half2_rn(A2.x, A2.y), h5 = __floats2half2_rn(A2.z, A2.w);
        __half2 h6 = __floats2half2_rn(A3.x, A3.y), h7 = __floats2half2_rn(A3.z, A3.w);
        uint4 s0 = make_uint4(*(unsigned*)&h0, *(unsigned*)&h1, *(unsigned*)&h2, *(unsigned*)&h3);
        uint4 s1 = make_uint4(*(unsigned*)&h4, *(unsigned*)&h5, *(unsigned*)&h6, *(unsigned*)&h7);
        *(uint4*)&out[(size_t)node * NFEAT + li * 16] = s0;
        *(uint4*)&out[(size_t)node * NFEAT + li * 16 + 8] = s1;
    }
}

// ---------------- mean pool (fp16 in): 64-row chunks, 2 row streams / block ----------------
__global__ void k_pool(const __half* __restrict__ h, const int* __restrict__ batch,
                       float* __restrict__ pooled, float* __restrict__ counts, int nN) {
    const int CHUNK = 64;
    int start = blockIdx.x * CHUNK;
    if (start >= nN) return;
    int end = min(start + CHUNK, nN);
    int f = threadIdx.x & 127;
    int sub = threadIdx.x >> 7;   // 2 interleaved streams
    float sum = 0.f;
    int cnt = 0;
    int cur = -1;
    for (int i = start + sub; i < end; i += 2) {
        int g = batch[i];
        if (g != cur) {
            if (cur >= 0) {
                atomicAdd(&pooled[cur * NFEAT + f], sum);
                if (f == 0) atomicAdd(&counts[cur], (float)cnt);
            }
            sum = 0.f; cnt = 0; cur = g;
        }
        sum += __half2float(h[(size_t)i * NFEAT + f]);
        cnt++;
    }
    if (cur >= 0) {
        atomicAdd(&pooled[cur * NFEAT + f], sum);
        if (f == 0) atomicAdd(&counts[cur], (float)cnt);
    }
}

// ---------------- classifier head: out[64,2] ----------------
__global__ void k_final(const float* __restrict__ pooled, const float* __restrict__ counts,
                        const float* __restrict__ Wc, const float* __restrict__ bc,
                        float* __restrict__ out) {
    int t = threadIdx.x;  // g = t>>1, class = t&1
    int g = t >> 1, c = t & 1;
    float inv = 1.0f / fmaxf(counts[g], 1.0f);
    float s = 0.f;
    for (int f = 0; f < NFEAT; ++f) s += pooled[g * NFEAT + f] * Wc[f * 2 + c];
    out[t] = s * inv + bc[c];
}

extern "C" void kernel_launch(void* const* d_in, const int* in_sizes, int n_in,
                              void* d_out, int out_size, void* d_ws, size_t ws_size,
                              hipStream_t stream) {
    const float* x   = (const float*)d_in[0];
    const int*   ei  = (const int*)d_in[1];
    const int*   bat = (const int*)d_in[2];
    const float* W1  = (const float*)d_in[3];
    const float* b1  = (const float*)d_in[4];
    const float* W2  = (const float*)d_in[5];
    const float* b2  = (const float*)d_in[6];
    const float* Wc  = (const float*)d_in[7];
    const float* bc  = (const float*)d_in[8];
    float* out = (float*)d_out;

    const int nN = in_sizes[0] / NFEAT;      // 50000
    const int nE = in_sizes[1] / 2;          // 800000
    const int* src = ei;
    const int* dst = ei + nE;

    char* ws = (char*)d_ws;
    size_t o = 0;
    auto alloc = [&](size_t bytes) -> char* {
        char* p = ws + o;
        o = (o + bytes + 255) & ~(size_t)255;
        return p;
    };
    // ---- zeroed region (one memset) ----
    unsigned int* cnt    = (unsigned int*)alloc((size_t)nN * 4);
    unsigned int* cursor = (unsigned int*)alloc((size_t)nN * 4);
    float* pooled        = (float*)alloc((size_t)NGRAPH * NFEAT * 4);
    float* counts        = (float*)alloc((size_t)NGRAPH * 4);
    size_t zero_bytes = o;
    // ---- rest ----
    int* off           = (int*)alloc(((size_t)nN + 1) * 4);
    unsigned int* bsum = (unsigned int*)alloc(256 * 4);
    unsigned int* boff = (unsigned int*)alloc(256 * 4);
    int2* epair        = (int2*)alloc((size_t)nE * 8);             // (src, norm)
    float* dinv        = (float*)alloc((size_t)nN * 4);
    __half* hg         = (__half*)alloc((size_t)nN * NFEAT * 2);   // gemm out / agg in
    __half* af         = (__half*)alloc((size_t)nN * NFEAT * 2);   // agg out / gemm2 in / pool in
    (void)ws_size; (void)n_in; (void)out_size;

    hipMemsetAsync(d_ws, 0, zero_bytes, stream);

    const int nb = (nN + 255) / 256;

    k_deg<<<(nE + 255) / 256, 256, 0, stream>>>(dst, cnt, nE);
    k_scan1<<<nb, 256, 0, stream>>>(cnt, bsum, dinv, nN);
    k_scan2<<<1, 256, 0, stream>>>(bsum, boff, off, nb, nN);
    k_scan3<<<nb, 256, 0, stream>>>(cnt, boff, off, nN);
    k_scatter<<<(nE + 255) / 256, 256, 0, stream>>>(src, dst, off, cursor, dinv, epair, nE);

    const int gemmGrid = 261;  // ceil(782 chunks / 3) — ~3 chunks of 64 rows per block

    // layer 1: hg = fp16(x @ W1) ; af = fp16(relu(agg(hg) + b1))
    k_gemm<float><<<gemmGrid, 256, 0, stream>>>(x, W1, hg, nN);
    k_agg<<<(nN + 3) / 4, 256, 0, stream>>>(hg, dinv, off, epair, b1, af, nN);
    // layer 2: hg = fp16(af @ W2) ; af = fp16(relu(agg(hg) + b2))
    k_gemm<__half><<<gemmGrid, 256, 0, stream>>>(af, W2, hg, nN);
    k_agg<<<(nN + 3) / 4, 256, 0, stream>>>(hg, dinv, off, epair, b2, af, nN);

    // mean pool + head
    k_pool<<<(nN + 63) / 64, 256, 0, stream>>>(af, bat, pooled, counts, nN);
    k_final<<<1, 128, 0, stream>>>(pooled, counts, Wc, bc, out);
}